// Round 4
// baseline (34.406 us; speedup 1.0000x reference)
//
#include <hip/hip_runtime.h>
#include <hip/hip_bf16.h>

// out[i] = a[i, argmax_j(z[i, 3+j])], j in {0,1,2}, first-max tie-break.
// B = 4194304 rows; z row = 8 f32 (32B), a row = 3 f32 (12B).
//
// All global accesses lane-contiguous (1024B/512B per wave instr). Stage only
// the 3 needed z words (colors) + a into LDS (12 KB total), then thread t
// computes rows t and t+256. Streaming data -> nontemporal hints.

#define ROWS_PER_BLOCK 512
#define NTHREADS 256

typedef float nfloat4 __attribute__((ext_vector_type(4)));
typedef float nfloat2 __attribute__((ext_vector_type(2)));

__global__ __launch_bounds__(NTHREADS) void color_val_lds(
    const float* __restrict__ z,
    const float* __restrict__ a,
    float* __restrict__ out)
{
    __shared__ float zc[ROWS_PER_BLOCK * 3];                // 6 KB: colors only
    __shared__ __align__(16) float as_[ROWS_PER_BLOCK * 3]; // 6 KB

    const int t = threadIdx.x;
    const size_t rowBase = (size_t)blockIdx.x * ROWS_PER_BLOCK;

    // ---- stage z colors: 1024 contiguous float4 loads per block ----
    // vec4 f covers row r = f>>1; even f holds z elems 0-3 (need [3]),
    // odd f holds elems 4-7 (need [0] = elem4, [1] = elem5).
    const nfloat4* zg = reinterpret_cast<const nfloat4*>(z) + rowBase * 2;
#pragma unroll
    for (int q = 0; q < 4; ++q) {
        int f = q * NTHREADS + t;
        nfloat4 v = __builtin_nontemporal_load(&zg[f]);
        int r = f >> 1;
        int odd = f & 1;
        zc[r * 3 + odd] = odd ? v[0] : v[3];   // elem4 (odd) / elem3 (even)
        if (odd) zc[r * 3 + 2] = v[1];         // elem5
    }

    // ---- stage a: 768 contiguous float2 loads per block ----
    const nfloat2* ag = reinterpret_cast<const nfloat2*>(a) + (rowBase * 3) / 2;
    nfloat2* as2 = reinterpret_cast<nfloat2*>(as_);
#pragma unroll
    for (int q = 0; q < 3; ++q) {
        int p2 = q * NTHREADS + t;
        as2[p2] = __builtin_nontemporal_load(&ag[p2]);
    }

    __syncthreads();

    // ---- compute: thread t handles rows t and t+256 ----
#pragma unroll
    for (int k = 0; k < 2; ++k) {
        int r = k * NTHREADS + t;
        float c0 = zc[r * 3 + 0];
        float c1 = zc[r * 3 + 1];
        float c2 = zc[r * 3 + 2];
        const float* ar = &as_[r * 3];
        float val = ar[0];
        float m = c0;
        if (c1 > m) { m = c1; val = ar[1]; }   // strict > => first-max tie-break
        if (c2 > m) {          val = ar[2]; }
        __builtin_nontemporal_store(val, &out[rowBase + r]);  // coalesced dword
    }
}

// generic tail (unused for B=4194304, kept for safety)
__global__ void color_val_tail(
    const float* __restrict__ z,
    const float* __restrict__ a,
    float* __restrict__ out,
    size_t start, size_t B)
{
    size_t i = start + blockIdx.x * blockDim.x + threadIdx.x;
    if (i >= B) return;
    float c0 = z[i * 8 + 3], c1 = z[i * 8 + 4], c2 = z[i * 8 + 5];
    float val = a[i * 3 + 0];
    float m = c0;
    if (c1 > m) { m = c1; val = a[i * 3 + 1]; }
    if (c2 > m) {          val = a[i * 3 + 2]; }
    out[i] = val;
}

extern "C" void kernel_launch(void* const* d_in, const int* in_sizes, int n_in,
                              void* d_out, int out_size, void* d_ws, size_t ws_size,
                              hipStream_t stream) {
    const float* z = (const float*)d_in[0];  // (B, 8) f32
    const float* a = (const float*)d_in[1];  // (B, 3) f32
    float* out = (float*)d_out;              // (B,)  f32

    size_t B = (size_t)out_size;             // 4194304
    size_t nfull = B / ROWS_PER_BLOCK;       // 8192
    size_t rem = B % ROWS_PER_BLOCK;         // 0

    if (nfull > 0)
        color_val_lds<<<(int)nfull, NTHREADS, 0, stream>>>(z, a, out);
    if (rem > 0) {
        size_t start = nfull * ROWS_PER_BLOCK;
        int blocks = (int)((rem + 255) / 256);
        color_val_tail<<<blocks, 256, 0, stream>>>(z, a, out, start, B);
    }
}